// Round 8
// baseline (419.230 us; speedup 1.0000x reference)
//
#include <hip/hip_runtime.h>
#include <hip/hip_bf16.h>

// CrossLocal: B=4, C=64, CI=32, cross 64x64 (Nc=4096), main 128x128.
// R8: persistent mega-kernel (512 blocks x 256 thr, guaranteed co-resident:
// LB(256,2) + 32KB LDS -> 2 blocks/CU x 256 CU). Phases: qkv -> grid barrier
// -> attn(R4 verbatim)+Wconv+stats -> grid barrier -> BN+upsample+residual.
// DIY device-scope barrier (init kernel zeros it; ws is poisoned each call).
// ws: Qb[bf16 4*4096*32] Kb[same] Vt[bf16 4*32*4096] out2[f32 4*64*4096]
//     stats[f32 128] bar[u32 2]

typedef __attribute__((ext_vector_type(8))) short bf16x8;
typedef __attribute__((ext_vector_type(4))) float f32x4;

#define LOG2E 1.4426950408889634f

static __device__ __forceinline__ unsigned short f2bf_bits(float x) {
    __hip_bfloat16 h = __float2bfloat16(x);
    return *(unsigned short*)&h;
}
static __device__ __forceinline__ unsigned int pk2bf(float a, float b) {
    __hip_bfloat162 h = __float22bfloat162_rn(make_float2(a, b));
    return *(unsigned int*)&h;
}

union __align__(16) Smem {
    float xs[64][128];                       // qkv staging (32 KB)
    struct {
        __hip_bfloat16 pbuf[4][2][16][40];   // attn P tiles
        float redbuf[2][64][12];
        float obuf[32][36];
    } at;
};

__global__ __launch_bounds__(256) void init_kernel(float* stats, unsigned* bar) {
    if (threadIdx.x < 128) stats[threadIdx.x] = 0.f;
    if (threadIdx.x < 2)   bar[threadIdx.x] = 0u;
}

// all 512 blocks co-resident by construction -> spin barrier is safe.
// __threadfence (agent scope) on both sides: release writers' L2, invalidate
// readers' L1/L2 (cross-XCD visibility, G16).
static __device__ __forceinline__ void grid_barrier(unsigned* bar, int idx) {
    __threadfence();
    __syncthreads();
    if (threadIdx.x == 0) {
        atomicAdd(&bar[idx], 1u);
        while (__hip_atomic_load(&bar[idx], __ATOMIC_RELAXED,
                                 __HIP_MEMORY_SCOPE_AGENT) < 512u) {
            __builtin_amdgcn_s_sleep(2);
        }
    }
    __syncthreads();
    __threadfence();
}

__global__ __launch_bounds__(256, 2) void mega_kernel(
    const float* __restrict__ mainf, const float* __restrict__ cross,
    const float* __restrict__ g_w,  const float* __restrict__ g_b,
    const float* __restrict__ th_w, const float* __restrict__ th_b,
    const float* __restrict__ ph_w, const float* __restrict__ ph_b,
    const float* __restrict__ w_w,  const float* __restrict__ w_b,
    const float* __restrict__ gamma, const float* __restrict__ beta,
    __hip_bfloat16* __restrict__ Qb, __hip_bfloat16* __restrict__ Kb,
    __hip_bfloat16* __restrict__ Vt, float* __restrict__ out2,
    float* __restrict__ stats, unsigned* __restrict__ bar,
    float* __restrict__ out)
{
    __shared__ Smem smem;
    const int tid = threadIdx.x;

    // ================= Phase 1: Q,K,V prep (384 working blocks) =================
    {
        const int kb = blockIdx.x;
        if (kb < 384) {
            const int kind = kb >> 7;            // 0=Q,1=K,2=V
            const int sub  = kb & 127;
            const int b    = sub >> 5;
            const int n0   = (sub & 31) << 7;    // 128 pixels per block
            const float* w  = (kind == 0) ? g_w : (kind == 1) ? th_w : ph_w;
            const float* bs = (kind == 0) ? g_b : (kind == 1) ? th_b : ph_b;

            if (kind < 2) {
                const float* src = cross + (((size_t)(b * 64)) << 12) + n0;
                const int jr = (tid & 31) << 2, c0 = tid >> 5;
#pragma unroll
                for (int it = 0; it < 8; ++it) {
                    int c = (it << 3) | c0;
                    *(float4*)&smem.xs[c][jr] = *(const float4*)(src + ((size_t)c << 12) + jr);
                }
            } else {
                const int px = tid & 127, chh = tid >> 7;
                const int n = n0 + px;
                const int i2 = (n >> 6) << 1, j2 = (n & 63) << 1;
                const float* src = mainf + (((size_t)(b * 64)) << 14) + i2 * 128 + j2;
#pragma unroll 4
                for (int cc = 0; cc < 32; ++cc) {
                    int c = (chh << 5) | cc;
                    const float2 a = *(const float2*)(src + ((size_t)c << 14));
                    const float2 d = *(const float2*)(src + ((size_t)c << 14) + 128);
                    smem.xs[c][px] = 0.25f * ((a.x + a.y) + (d.x + d.y));
                }
            }
            __syncthreads();

            const int px = tid & 127, cih = tid >> 7, ci0 = cih << 4;
            float acc[16];
#pragma unroll
            for (int j = 0; j < 16; ++j) acc[j] = bs[ci0 + j];
#pragma unroll 4
            for (int c = 0; c < 64; ++c) {
                float x = smem.xs[c][px];
#pragma unroll
                for (int j = 0; j < 16; ++j)
                    acc[j] = fmaf(w[((ci0 + j) << 6) + c], x, acc[j]);
            }
            const int n = n0 + px;
            const int pix = (b << 12) + n;
            if (kind < 2) {
                if (kind == 0) {
#pragma unroll
                    for (int j = 0; j < 16; ++j) acc[j] *= LOG2E;
                }
                unsigned int u[8];
#pragma unroll
                for (int i = 0; i < 8; ++i)
                    u[i] = (unsigned int)f2bf_bits(acc[2 * i]) |
                           ((unsigned int)f2bf_bits(acc[2 * i + 1]) << 16);
                uint4* d4 = (uint4*)(((kind == 0) ? Qb : Kb) + (size_t)pix * 32 + ci0);
                d4[0] = make_uint4(u[0], u[1], u[2], u[3]);
                d4[1] = make_uint4(u[4], u[5], u[6], u[7]);
            } else {
#pragma unroll
                for (int j = 0; j < 16; ++j)
                    Vt[((size_t)((b << 5) | (ci0 + j)) << 12) + n] = __float2bfloat16(acc[j]);
            }
        }
    }
    grid_barrier(bar, 0);

    // ================= Phase 2: attention + W conv + stats (R4 verbatim) =========
    {
        const int lane = tid & 63, w = tid >> 6;
        const int lo = lane & 15, c = lane >> 4;
        const int kh = w & 1, qg = w >> 1;
        const int b = blockIdx.x >> 7, bx = blockIdx.x & 127;
        const int qbase = (bx << 5) + (qg << 4);

        const bf16x8 aq = *(const bf16x8*)(Qb + (((size_t)(b << 12) + qbase + lo) << 5) + (c << 3));
        const __hip_bfloat16* Kbb = Kb + ((size_t)(b << 12) << 5);
        const __hip_bfloat16* Vbb = Vt + ((size_t)(b << 5) << 12);

        f32x4 acc0 = {0.f,0.f,0.f,0.f}, acc1 = {0.f,0.f,0.f,0.f};
        float den = 0.f;
        const f32x4 z = {0.f,0.f,0.f,0.f};
        const int kq = kh << 11;
#define LDK(k)      (*(const bf16x8*)(Kbb + ((size_t)((k) + lo) << 5) + (c << 3)))
#define LDV(k, cio) (*(const bf16x8*)(Vbb + ((size_t)(lo + (cio)) << 12) + (k) + (c << 3)))

        bf16x8 k0c = LDK(kq),      k1c = LDK(kq + 16);
        bf16x8 vB0 = LDV(kq, 0),   vB1 = LDV(kq, 16);
        bf16x8 k0n = LDK(kq + 32), k1n = LDK(kq + 48);
        bf16x8 vN0 = LDV(kq + 32, 0), vN1 = LDV(kq + 32, 16);
        bf16x8 ap;

        {
            f32x4 s0 = __builtin_amdgcn_mfma_f32_16x16x32_bf16(k0c, aq, z, 0, 0, 0);
            f32x4 s1 = __builtin_amdgcn_mfma_f32_16x16x32_bf16(k1c, aq, z, 0, 0, 0);
            float p0 = __builtin_amdgcn_exp2f(s0[0]), p1 = __builtin_amdgcn_exp2f(s0[1]);
            float p2 = __builtin_amdgcn_exp2f(s0[2]), p3 = __builtin_amdgcn_exp2f(s0[3]);
            float q0 = __builtin_amdgcn_exp2f(s1[0]), q1 = __builtin_amdgcn_exp2f(s1[1]);
            float q2 = __builtin_amdgcn_exp2f(s1[2]), q3 = __builtin_amdgcn_exp2f(s1[3]);
            den += ((p0 + p1) + (p2 + p3)) + ((q0 + q1) + (q2 + q3));
            uint2 wv0 = make_uint2(pk2bf(p0, p1), pk2bf(p2, p3));
            uint2 wv1 = make_uint2(pk2bf(q0, q1), pk2bf(q2, q3));
            *(uint2*)&smem.at.pbuf[w][0][lo][c << 2]        = wv0;
            *(uint2*)&smem.at.pbuf[w][0][lo][16 + (c << 2)] = wv1;
            ap = *(const bf16x8*)&smem.at.pbuf[w][0][lo][c << 3];
        }

#pragma unroll 2
        for (int ch = 1; ch < 64; ++ch) {
            const int kn = kq + ((ch + 1) & 63) * 32;
            bf16x8 vA0 = vB0, vA1 = vB1;
            vB0 = vN0; vB1 = vN1;
            k0c = k0n; k1c = k1n;
            k0n = LDK(kn); k1n = LDK(kn + 16);
            vN0 = LDV(kn, 0); vN1 = LDV(kn, 16);

            f32x4 s0 = __builtin_amdgcn_mfma_f32_16x16x32_bf16(k0c, aq, z, 0, 0, 0);
            f32x4 s1 = __builtin_amdgcn_mfma_f32_16x16x32_bf16(k1c, aq, z, 0, 0, 0);
            float p0 = __builtin_amdgcn_exp2f(s0[0]), p1 = __builtin_amdgcn_exp2f(s0[1]);
            float p2 = __builtin_amdgcn_exp2f(s0[2]), p3 = __builtin_amdgcn_exp2f(s0[3]);
            float q0 = __builtin_amdgcn_exp2f(s1[0]), q1 = __builtin_amdgcn_exp2f(s1[1]);
            float q2 = __builtin_amdgcn_exp2f(s1[2]), q3 = __builtin_amdgcn_exp2f(s1[3]);
            den += ((p0 + p1) + (p2 + p3)) + ((q0 + q1) + (q2 + q3));
            uint2 wv0 = make_uint2(pk2bf(p0, p1), pk2bf(p2, p3));
            uint2 wv1 = make_uint2(pk2bf(q0, q1), pk2bf(q2, q3));
            *(uint2*)&smem.at.pbuf[w][ch & 1][lo][c << 2]        = wv0;
            *(uint2*)&smem.at.pbuf[w][ch & 1][lo][16 + (c << 2)] = wv1;

            acc0 = __builtin_amdgcn_mfma_f32_16x16x32_bf16(ap, vA0, acc0, 0, 0, 0);
            acc1 = __builtin_amdgcn_mfma_f32_16x16x32_bf16(ap, vA1, acc1, 0, 0, 0);

            ap = *(const bf16x8*)&smem.at.pbuf[w][ch & 1][lo][c << 3];
        }
        acc0 = __builtin_amdgcn_mfma_f32_16x16x32_bf16(ap, vB0, acc0, 0, 0, 0);
        acc1 = __builtin_amdgcn_mfma_f32_16x16x32_bf16(ap, vB1, acc1, 0, 0, 0);
#undef LDK
#undef LDV

        den += __shfl_xor(den, 16);
        den += __shfl_xor(den, 32);

        if (kh) {
            f32x4* rb = (f32x4*)&smem.at.redbuf[qg][lane][0];
            rb[0] = acc0; rb[1] = acc1;
            f32x4 dv = {den, 0.f, 0.f, 0.f};
            rb[2] = dv;
        }
        __syncthreads();
        if (kh == 0) {
            const f32x4* rb = (const f32x4*)&smem.at.redbuf[qg][lane][0];
            f32x4 a0 = rb[0], a1 = rb[1], dv = rb[2];
            acc0 += a0; acc1 += a1;
            den += dv[0];
#pragma unroll
            for (int r = 0; r < 4; ++r) {
                float inv = 1.0f / __shfl(den, (c << 2) | r);
                smem.at.obuf[(qg << 4) | (c << 2) | r][lo]      = acc0[r] * inv;
                smem.at.obuf[(qg << 4) | (c << 2) | r][16 + lo] = acc1[r] * inv;
            }
        }
        __syncthreads();

        const int q = tid & 31, cog = tid >> 5;   // 8 co per thread
        float ov[32];
        const float4* orow = (const float4*)&smem.at.obuf[q][0];
#pragma unroll
        for (int k4 = 0; k4 < 8; ++k4) {
            float4 t = orow[k4];
            ov[4*k4] = t.x; ov[4*k4+1] = t.y; ov[4*k4+2] = t.z; ov[4*k4+3] = t.w;
        }
        float* dstbase = out2 + (((size_t)(b << 6)) << 12) + (bx << 5) + q;
        float vs[8], vs2[8];
#pragma unroll
        for (int kk = 0; kk < 8; ++kk) {
            int co = (kk << 3) | cog;
            const float4* wr = (const float4*)&w_w[co << 5];
            float acc = w_b[co];
#pragma unroll
            for (int k4 = 0; k4 < 8; ++k4) {
                float4 t = wr[k4];
                acc = fmaf(t.x, ov[4*k4],   acc);
                acc = fmaf(t.y, ov[4*k4+1], acc);
                acc = fmaf(t.z, ov[4*k4+2], acc);
                acc = fmaf(t.w, ov[4*k4+3], acc);
            }
            dstbase[(size_t)co << 12] = acc;
            vs[kk] = acc; vs2[kk] = acc * acc;
        }
        // reduce over the 32 q-lanes sharing cog (xor offsets stay in half-wave)
#pragma unroll
        for (int off = 1; off < 32; off <<= 1) {
#pragma unroll
            for (int kk = 0; kk < 8; ++kk) {
                vs[kk]  += __shfl_xor(vs[kk],  off);
                vs2[kk] += __shfl_xor(vs2[kk], off);
            }
        }
        if ((lane & 31) == 0) {
#pragma unroll
            for (int kk = 0; kk < 8; ++kk) {
                int co = (kk << 3) | cog;
                atomicAdd(&stats[co],      vs[kk]);
                atomicAdd(&stats[64 + co], vs2[kk]);
            }
        }
    }
    grid_barrier(bar, 1);

    // ================= Phase 3: BN + bilinear 64->128 + residual =================
    {
        const int flat = blockIdx.x * 256 + tid;
#pragma unroll 2
        for (int u = 0; u < 8; ++u) {
            const int gid = flat + (u << 17);
            const int j4 = (gid & 31) << 2;
            const int i  = (gid >> 5) & 127;
            const int co = (gid >> 12) & 63;
            const int b  = gid >> 18;

            float mean = stats[co] * (1.0f / 16384.0f);
            float var  = stats[64 + co] * (1.0f / 16384.0f) - mean * mean;
            float inv  = rsqrtf(var + 1e-5f);
            float scale = gamma[co] * inv;
            float shift = beta[co] - mean * scale;

            int ih = i >> 1;
            int k0, k1; float wi;
            if (i & 1)       { k0 = ih;     k1 = (ih < 63) ? ih + 1 : 63; wi = 0.25f; }
            else if (ih == 0){ k0 = 0;      k1 = 0;                       wi = 0.0f;  }
            else             { k0 = ih - 1; k1 = ih;                      wi = 0.75f; }

            const float* p0r = out2 + ((size_t)((b << 6) | co) << 12) + (k0 << 6);
            const float* p1r = out2 + ((size_t)((b << 6) | co) << 12) + (k1 << 6);

            float res[4];
#pragma unroll
            for (int jj = 0; jj < 4; ++jj) {
                int j = j4 | jj;
                int il = j >> 1;
                int l0, l1; float wj;
                if (j & 1)       { l0 = il;     l1 = (il < 63) ? il + 1 : 63; wj = 0.25f; }
                else if (il == 0){ l0 = 0;      l1 = 0;                       wj = 0.0f;  }
                else             { l0 = il - 1; l1 = il;                      wj = 0.75f; }
                float v00 = p0r[l0], v01 = p0r[l1];
                float v10 = p1r[l0], v11 = p1r[l1];
                float top = v00 + wj * (v01 - v00);
                float bot = v10 + wj * (v11 - v10);
                float v = top + wi * (bot - top);
                res[jj] = fmaf(v, scale, shift);
            }
            size_t idx = (((size_t)((b << 6) | co)) << 14) + (i << 7) + j4;
            float4 m4 = *(const float4*)(mainf + idx);
            *(float4*)(out + idx) = make_float4(res[0] + m4.x, res[1] + m4.y,
                                                res[2] + m4.z, res[3] + m4.w);
        }
    }
}

extern "C" void kernel_launch(void* const* d_in, const int* in_sizes, int n_in,
                              void* d_out, int out_size, void* d_ws, size_t ws_size,
                              hipStream_t stream)
{
    const float* mainf = (const float*)d_in[0];
    const float* cross = (const float*)d_in[1];
    const float* g_w   = (const float*)d_in[2];
    const float* g_b   = (const float*)d_in[3];
    const float* th_w  = (const float*)d_in[4];
    const float* th_b  = (const float*)d_in[5];
    const float* ph_w  = (const float*)d_in[6];
    const float* ph_b  = (const float*)d_in[7];
    const float* w_w   = (const float*)d_in[8];
    const float* w_b   = (const float*)d_in[9];
    const float* gamma = (const float*)d_in[10];
    const float* beta  = (const float*)d_in[11];
    float* out = (float*)d_out;

    __hip_bfloat16* Qb = (__hip_bfloat16*)d_ws;     // 4*4096*32
    __hip_bfloat16* Kb = Qb + 524288;
    __hip_bfloat16* Vt = Kb + 524288;               // [b][ci][4096]
    float* out2  = (float*)(Vt + 524288);           // 4*64*4096
    float* stats = out2 + 1048576;                  // 128
    unsigned* bar = (unsigned*)(stats + 128);       // 2

    init_kernel<<<1, 256, 0, stream>>>(stats, bar);
    mega_kernel<<<512, 256, 0, stream>>>(mainf, cross, g_w, g_b, th_w, th_b,
                                         ph_w, ph_b, w_w, w_b, gamma, beta,
                                         Qb, Kb, Vt, out2, stats, bar, out);
}

// Round 9
// 168.001 us; speedup vs baseline: 2.4954x; 2.4954x over previous
//
#include <hip/hip_runtime.h>
#include <hip/hip_bf16.h>

// CrossLocal: B=4, C=64, CI=32, cross 64x64 (Nc=4096), main 128x128.
// R9: attn = R7's proven pipelined loop body inside R5's 1024-block shell
// (16q x 4-way key split, 32 chunks/wave) -> 4 blocks/CU, 2x TLP.
// qkv = R8 phase-1 standalone (384 blocks, 32KB LDS). stats/up = R7 verbatim.
// ws: Qb[bf16 4*4096*32] Kb[same] Vt[bf16 4*32*4096] out2[f32 4*64*4096] stats1[512]

typedef __attribute__((ext_vector_type(8))) short bf16x8;
typedef __attribute__((ext_vector_type(4))) float f32x4;

#define LOG2E 1.4426950408889634f

static __device__ __forceinline__ unsigned short f2bf_bits(float x) {
    __hip_bfloat16 h = __float2bfloat16(x);
    return *(unsigned short*)&h;
}
static __device__ __forceinline__ unsigned int pk2bf(float a, float b) {
    __hip_bfloat162 h = __float22bfloat162_rn(make_float2(a, b));
    return *(unsigned int*)&h;
}

// ---------------- Kernel 1: Q,K,V prep (384 blocks, 128 px, 16 ci/thread) ----------------
__global__ __launch_bounds__(256) void qkv_kernel(
    const float* __restrict__ cross, const float* __restrict__ mainf,
    const float* __restrict__ g_w,  const float* __restrict__ g_b,
    const float* __restrict__ th_w, const float* __restrict__ th_b,
    const float* __restrict__ ph_w, const float* __restrict__ ph_b,
    __hip_bfloat16* __restrict__ Qb, __hip_bfloat16* __restrict__ Kb,
    __hip_bfloat16* __restrict__ Vt)
{
    __shared__ float xs[64][128];            // 32 KB
    const int kind = blockIdx.x >> 7;        // 0=Q,1=K,2=V
    const int sub  = blockIdx.x & 127;
    const int b    = sub >> 5;
    const int n0   = (sub & 31) << 7;        // 128 pixels per block
    const int tid  = threadIdx.x;
    const float* w  = (kind == 0) ? g_w : (kind == 1) ? th_w : ph_w;
    const float* bs = (kind == 0) ? g_b : (kind == 1) ? th_b : ph_b;

    if (kind < 2) {
        const float* src = cross + (((size_t)(b * 64)) << 12) + n0;
        const int jr = (tid & 31) << 2, c0 = tid >> 5;
#pragma unroll
        for (int it = 0; it < 8; ++it) {
            int c = (it << 3) | c0;
            *(float4*)&xs[c][jr] = *(const float4*)(src + ((size_t)c << 12) + jr);
        }
    } else {
        const int px = tid & 127, chh = tid >> 7;
        const int n = n0 + px;
        const int i2 = (n >> 6) << 1, j2 = (n & 63) << 1;
        const float* src = mainf + (((size_t)(b * 64)) << 14) + i2 * 128 + j2;
#pragma unroll 4
        for (int cc = 0; cc < 32; ++cc) {
            int c = (chh << 5) | cc;
            const float2 a = *(const float2*)(src + ((size_t)c << 14));
            const float2 d = *(const float2*)(src + ((size_t)c << 14) + 128);
            xs[c][px] = 0.25f * ((a.x + a.y) + (d.x + d.y));
        }
    }
    __syncthreads();

    const int px = tid & 127, cih = tid >> 7, ci0 = cih << 4;
    float acc[16];
#pragma unroll
    for (int j = 0; j < 16; ++j) acc[j] = bs[ci0 + j];
#pragma unroll 4
    for (int c = 0; c < 64; ++c) {
        float x = xs[c][px];
#pragma unroll
        for (int j = 0; j < 16; ++j)
            acc[j] = fmaf(w[((ci0 + j) << 6) + c], x, acc[j]);
    }
    const int n = n0 + px;
    const int pix = (b << 12) + n;
    if (kind < 2) {
        if (kind == 0) {
#pragma unroll
            for (int j = 0; j < 16; ++j) acc[j] *= LOG2E;
        }
        unsigned int u[8];
#pragma unroll
        for (int i = 0; i < 8; ++i)
            u[i] = (unsigned int)f2bf_bits(acc[2 * i]) |
                   ((unsigned int)f2bf_bits(acc[2 * i + 1]) << 16);
        uint4* d4 = (uint4*)(((kind == 0) ? Qb : Kb) + (size_t)pix * 32 + ci0);
        d4[0] = make_uint4(u[0], u[1], u[2], u[3]);
        d4[1] = make_uint4(u[4], u[5], u[6], u[7]);
    } else {
#pragma unroll
        for (int j = 0; j < 16; ++j)
            Vt[((size_t)((b << 5) | (ci0 + j)) << 12) + n] = __float2bfloat16(acc[j]);
    }
}

// ---------------- Kernel 2: S^T-form MFMA flash attention + W conv ----------------
// grid (256 qtiles of 16, 4 batch) x 256 thr. Wave w owns keys [w*1024,+1024),
// 32 chunks. Loop body identical to R7's (protect the schedule).
__global__ __launch_bounds__(256) void attn_mfma(
    const __hip_bfloat16* __restrict__ Qb, const __hip_bfloat16* __restrict__ Kb,
    const __hip_bfloat16* __restrict__ Vt, const float* __restrict__ w_w,
    const float* __restrict__ w_b, float* __restrict__ out2)
{
    __shared__ __align__(16) __hip_bfloat16 pbuf[4][2][16][40];
    __shared__ __align__(16) float redbuf[3][64][12];
    __shared__ __align__(16) float obuf[16][36];
    const int tid = threadIdx.x, lane = tid & 63, w = tid >> 6;
    const int lo = lane & 15, c = lane >> 4;
    const int b = blockIdx.y, qbase = blockIdx.x << 4;

    const bf16x8 aq = *(const bf16x8*)(Qb + (((size_t)(b << 12) + qbase + lo) << 5) + (c << 3));
    const __hip_bfloat16* Kbb = Kb + ((size_t)(b << 12) << 5);
    const __hip_bfloat16* Vbb = Vt + ((size_t)(b << 5) << 12);

    f32x4 acc0 = {0.f,0.f,0.f,0.f}, acc1 = {0.f,0.f,0.f,0.f};
    float den = 0.f;
    const f32x4 z = {0.f,0.f,0.f,0.f};
    const int kq = w << 10;
#define LDK(k)      (*(const bf16x8*)(Kbb + ((size_t)((k) + lo) << 5) + (c << 3)))
#define LDV(k, cio) (*(const bf16x8*)(Vbb + ((size_t)(lo + (cio)) << 12) + (k) + (c << 3)))

    bf16x8 k0c = LDK(kq),      k1c = LDK(kq + 16);
    bf16x8 vB0 = LDV(kq, 0),   vB1 = LDV(kq, 16);
    bf16x8 k0n = LDK(kq + 32), k1n = LDK(kq + 48);
    bf16x8 vN0 = LDV(kq + 32, 0), vN1 = LDV(kq + 32, 16);
    bf16x8 ap;

    {
        f32x4 s0 = __builtin_amdgcn_mfma_f32_16x16x32_bf16(k0c, aq, z, 0, 0, 0);
        f32x4 s1 = __builtin_amdgcn_mfma_f32_16x16x32_bf16(k1c, aq, z, 0, 0, 0);
        float p0 = __builtin_amdgcn_exp2f(s0[0]), p1 = __builtin_amdgcn_exp2f(s0[1]);
        float p2 = __builtin_amdgcn_exp2f(s0[2]), p3 = __builtin_amdgcn_exp2f(s0[3]);
        float q0 = __builtin_amdgcn_exp2f(s1[0]), q1 = __builtin_amdgcn_exp2f(s1[1]);
        float q2 = __builtin_amdgcn_exp2f(s1[2]), q3 = __builtin_amdgcn_exp2f(s1[3]);
        den += ((p0 + p1) + (p2 + p3)) + ((q0 + q1) + (q2 + q3));
        uint2 wv0 = make_uint2(pk2bf(p0, p1), pk2bf(p2, p3));
        uint2 wv1 = make_uint2(pk2bf(q0, q1), pk2bf(q2, q3));
        *(uint2*)&pbuf[w][0][lo][c << 2]        = wv0;
        *(uint2*)&pbuf[w][0][lo][16 + (c << 2)] = wv1;
        ap = *(const bf16x8*)&pbuf[w][0][lo][c << 3];
    }

#pragma unroll 2
    for (int ch = 1; ch < 32; ++ch) {
        const int kn = kq + ((ch + 1) & 31) * 32;
        bf16x8 vA0 = vB0, vA1 = vB1;
        vB0 = vN0; vB1 = vN1;
        k0c = k0n; k1c = k1n;
        k0n = LDK(kn); k1n = LDK(kn + 16);
        vN0 = LDV(kn, 0); vN1 = LDV(kn, 16);

        f32x4 s0 = __builtin_amdgcn_mfma_f32_16x16x32_bf16(k0c, aq, z, 0, 0, 0);
        f32x4 s1 = __builtin_amdgcn_mfma_f32_16x16x32_bf16(k1c, aq, z, 0, 0, 0);
        float p0 = __builtin_amdgcn_exp2f(s0[0]), p1 = __builtin_amdgcn_exp2f(s0[1]);
        float p2 = __builtin_amdgcn_exp2f(s0[2]), p3 = __builtin_amdgcn_exp2f(s0[3]);
        float q0 = __builtin_amdgcn_exp2f(s1[0]), q1 = __builtin_amdgcn_exp2f(s1[1]);
        float q2 = __builtin_amdgcn_exp2f(s1[2]), q3 = __builtin_amdgcn_exp2f(s1[3]);
        den += ((p0 + p1) + (p2 + p3)) + ((q0 + q1) + (q2 + q3));
        uint2 wv0 = make_uint2(pk2bf(p0, p1), pk2bf(p2, p3));
        uint2 wv1 = make_uint2(pk2bf(q0, q1), pk2bf(q2, q3));
        *(uint2*)&pbuf[w][ch & 1][lo][c << 2]        = wv0;
        *(uint2*)&pbuf[w][ch & 1][lo][16 + (c << 2)] = wv1;

        acc0 = __builtin_amdgcn_mfma_f32_16x16x32_bf16(ap, vA0, acc0, 0, 0, 0);
        acc1 = __builtin_amdgcn_mfma_f32_16x16x32_bf16(ap, vA1, acc1, 0, 0, 0);

        ap = *(const bf16x8*)&pbuf[w][ch & 1][lo][c << 3];
    }
    acc0 = __builtin_amdgcn_mfma_f32_16x16x32_bf16(ap, vB0, acc0, 0, 0, 0);
    acc1 = __builtin_amdgcn_mfma_f32_16x16x32_bf16(ap, vB1, acc1, 0, 0, 0);
#undef LDK
#undef LDV

    den += __shfl_xor(den, 16);
    den += __shfl_xor(den, 32);

    if (w) {
        f32x4* rb = (f32x4*)&redbuf[w - 1][lane][0];
        rb[0] = acc0; rb[1] = acc1;
        f32x4 dv = {den, 0.f, 0.f, 0.f};
        rb[2] = dv;
    }
    __syncthreads();
    if (w == 0) {
#pragma unroll
        for (int ww = 0; ww < 3; ++ww) {
            const f32x4* rb = (const f32x4*)&redbuf[ww][lane][0];
            f32x4 a0 = rb[0], a1 = rb[1], dv = rb[2];
            acc0 += a0; acc1 += a1;
            den += dv[0];
        }
#pragma unroll
        for (int r = 0; r < 4; ++r) {
            float inv = 1.0f / __shfl(den, (c << 2) | r);
            obuf[(c << 2) | r][lo]      = acc0[r] * inv;
            obuf[(c << 2) | r][16 + lo] = acc1[r] * inv;
        }
    }
    __syncthreads();

    // ---- fused W 1x1 conv over the 16-query tile ----
    const int q = tid & 15, cog = tid >> 4;   // 4 co per thread
    float ov[32];
    const float4* orow = (const float4*)&obuf[q][0];
#pragma unroll
    for (int k4 = 0; k4 < 8; ++k4) {
        float4 t = orow[k4];
        ov[4*k4] = t.x; ov[4*k4+1] = t.y; ov[4*k4+2] = t.z; ov[4*k4+3] = t.w;
    }
    float* dstbase = out2 + (((size_t)(b << 6)) << 12) + qbase + q;
#pragma unroll
    for (int kk = 0; kk < 4; ++kk) {
        int co = (kk << 4) | cog;
        const float4* wr = (const float4*)&w_w[co << 5];
        float acc = w_b[co];
#pragma unroll
        for (int k4 = 0; k4 < 8; ++k4) {
            float4 t = wr[k4];
            acc = fmaf(t.x, ov[4*k4],   acc);
            acc = fmaf(t.y, ov[4*k4+1], acc);
            acc = fmaf(t.z, ov[4*k4+2], acc);
            acc = fmaf(t.w, ov[4*k4+3], acc);
        }
        dstbase[(size_t)co << 12] = acc;
    }
}

// ---------------- Kernel 3: BN partial statistics (per channel, per batch) ----------------
__global__ __launch_bounds__(256) void stats_kernel(
    const float* __restrict__ out2, float* __restrict__ stats1)
{
    int co = blockIdx.x >> 2, b = blockIdx.x & 3, t = threadIdx.x;
    const float* p = out2 + ((size_t)((b << 6) | co) << 12);
    float s = 0.f, s2 = 0.f;
#pragma unroll
    for (int ii = 0; ii < 16; ++ii) {
        float v = p[(ii << 8) | t];
        s += v; s2 = fmaf(v, v, s2);
    }
    __shared__ float rs[256], rs2[256];
    rs[t] = s; rs2[t] = s2;
    __syncthreads();
    for (int off = 128; off > 0; off >>= 1) {
        if (t < off) { rs[t] += rs[t + off]; rs2[t] += rs2[t + off]; }
        __syncthreads();
    }
    if (t == 0) {
        stats1[blockIdx.x * 2]     = rs[0];
        stats1[blockIdx.x * 2 + 1] = rs2[0];
    }
}

// ---------------- Kernel 4: BN + bilinear 64->128 + residual (float4) ----------------
__global__ __launch_bounds__(256) void up_kernel(
    const float* __restrict__ out2, const float* __restrict__ stats1,
    const float* __restrict__ gamma, const float* __restrict__ beta,
    const float* __restrict__ mainf, float* __restrict__ out)
{
    int gid = blockIdx.x * 256 + threadIdx.x;   // < 4*64*128*32
    int j4 = (gid & 31) << 2;
    int i  = (gid >> 5) & 127;
    int co = (gid >> 12) & 63;            // uniform within a block
    int b  = gid >> 18;

    float sm = 0.f, sq = 0.f;
#pragma unroll
    for (int bb = 0; bb < 4; ++bb) {
        sm += stats1[((co << 2) | bb) * 2];
        sq += stats1[((co << 2) | bb) * 2 + 1];
    }
    float mean = sm * (1.0f / 16384.0f);
    float var  = sq * (1.0f / 16384.0f) - mean * mean;
    float inv  = rsqrtf(var + 1e-5f);
    float scale = gamma[co] * inv;
    float shift = beta[co] - mean * scale;

    int ih = i >> 1;
    int k0, k1; float wi;
    if (i & 1)       { k0 = ih;     k1 = (ih < 63) ? ih + 1 : 63; wi = 0.25f; }
    else if (ih == 0){ k0 = 0;      k1 = 0;                       wi = 0.0f;  }
    else             { k0 = ih - 1; k1 = ih;                      wi = 0.75f; }

    const float* p0r = out2 + ((size_t)((b << 6) | co) << 12) + (k0 << 6);
    const float* p1r = out2 + ((size_t)((b << 6) | co) << 12) + (k1 << 6);

    float res[4];
#pragma unroll
    for (int jj = 0; jj < 4; ++jj) {
        int j = j4 | jj;
        int il = j >> 1;
        int l0, l1; float wj;
        if (j & 1)       { l0 = il;     l1 = (il < 63) ? il + 1 : 63; wj = 0.25f; }
        else if (il == 0){ l0 = 0;      l1 = 0;                       wj = 0.0f;  }
        else             { l0 = il - 1; l1 = il;                      wj = 0.75f; }
        float v00 = p0r[l0], v01 = p0r[l1];
        float v10 = p1r[l0], v11 = p1r[l1];
        float top = v00 + wj * (v01 - v00);
        float bot = v10 + wj * (v11 - v10);
        float v = top + wi * (bot - top);
        res[jj] = fmaf(v, scale, shift);
    }
    size_t idx = (((size_t)((b << 6) | co)) << 14) + (i << 7) + j4;
    float4 m4 = *(const float4*)(mainf + idx);
    *(float4*)(out + idx) = make_float4(res[0] + m4.x, res[1] + m4.y,
                                        res[2] + m4.z, res[3] + m4.w);
}

extern "C" void kernel_launch(void* const* d_in, const int* in_sizes, int n_in,
                              void* d_out, int out_size, void* d_ws, size_t ws_size,
                              hipStream_t stream)
{
    const float* mainf = (const float*)d_in[0];
    const float* cross = (const float*)d_in[1];
    const float* g_w   = (const float*)d_in[2];
    const float* g_b   = (const float*)d_in[3];
    const float* th_w  = (const float*)d_in[4];
    const float* th_b  = (const float*)d_in[5];
    const float* ph_w  = (const float*)d_in[6];
    const float* ph_b  = (const float*)d_in[7];
    const float* w_w   = (const float*)d_in[8];
    const float* w_b   = (const float*)d_in[9];
    const float* gamma = (const float*)d_in[10];
    const float* beta  = (const float*)d_in[11];
    float* out = (float*)d_out;

    __hip_bfloat16* Qb = (__hip_bfloat16*)d_ws;     // 4*4096*32
    __hip_bfloat16* Kb = Qb + 524288;
    __hip_bfloat16* Vt = Kb + 524288;               // [b][ci][4096]
    float* out2   = (float*)(Vt + 524288);          // 4*64*4096
    float* stats1 = out2 + 1048576;                 // 512

    qkv_kernel<<<384, 256, 0, stream>>>(cross, mainf, g_w, g_b, th_w, th_b,
                                        ph_w, ph_b, Qb, Kb, Vt);
    attn_mfma<<<dim3(256, 4), 256, 0, stream>>>(Qb, Kb, Vt, w_w, w_b, out2);
    stats_kernel<<<256, 256, 0, stream>>>(out2, stats1);
    up_kernel<<<4096, 256, 0, stream>>>(out2, stats1, gamma, beta, mainf, out);
}

// Round 10
// 147.257 us; speedup vs baseline: 2.8469x; 1.1409x over previous
//
#include <hip/hip_runtime.h>
#include <hip/hip_bf16.h>

// CrossLocal: B=4, C=64, CI=32, cross 64x64 (Nc=4096), main 128x128.
// R10: 32x32x16-MFMA attention, LDS-free inner loop. S^T = K.Q^T with
// K-row permutation sigma(m)=swapbits2,3(m) makes each lane's 16 exps land
// register-natively as the two PV A-fragments (keys 8h..8h+7 / 16+8h..+7 for
// query lane&31). PV consumes the PREVIOUS iteration's packed P (register
// deferral, R4's decoupling without LDS). 512 blocks: 32q x 4-way key split.
// qkv/stats/up verbatim R9.
// ws: Qb[bf16 4*4096*32] Kb[same] Vt[bf16 4*32*4096] out2[f32 4*64*4096] stats1[512]

typedef __attribute__((ext_vector_type(8))) short bf16x8;
typedef __attribute__((ext_vector_type(4))) float f32x4;
typedef __attribute__((ext_vector_type(16))) float f32x16;

#define LOG2E 1.4426950408889634f

static __device__ __forceinline__ unsigned short f2bf_bits(float x) {
    __hip_bfloat16 h = __float2bfloat16(x);
    return *(unsigned short*)&h;
}
static __device__ __forceinline__ unsigned int pk2bf(float a, float b) {
    __hip_bfloat162 h = __float22bfloat162_rn(make_float2(a, b));
    return *(unsigned int*)&h;
}

// ---------------- Kernel 1: Q,K,V prep (R9 verbatim) ----------------
__global__ __launch_bounds__(256) void qkv_kernel(
    const float* __restrict__ cross, const float* __restrict__ mainf,
    const float* __restrict__ g_w,  const float* __restrict__ g_b,
    const float* __restrict__ th_w, const float* __restrict__ th_b,
    const float* __restrict__ ph_w, const float* __restrict__ ph_b,
    __hip_bfloat16* __restrict__ Qb, __hip_bfloat16* __restrict__ Kb,
    __hip_bfloat16* __restrict__ Vt)
{
    __shared__ float xs[64][128];            // 32 KB
    const int kind = blockIdx.x >> 7;        // 0=Q,1=K,2=V
    const int sub  = blockIdx.x & 127;
    const int b    = sub >> 5;
    const int n0   = (sub & 31) << 7;        // 128 pixels per block
    const int tid  = threadIdx.x;
    const float* w  = (kind == 0) ? g_w : (kind == 1) ? th_w : ph_w;
    const float* bs = (kind == 0) ? g_b : (kind == 1) ? th_b : ph_b;

    if (kind < 2) {
        const float* src = cross + (((size_t)(b * 64)) << 12) + n0;
        const int jr = (tid & 31) << 2, c0 = tid >> 5;
#pragma unroll
        for (int it = 0; it < 8; ++it) {
            int c = (it << 3) | c0;
            *(float4*)&xs[c][jr] = *(const float4*)(src + ((size_t)c << 12) + jr);
        }
    } else {
        const int px = tid & 127, chh = tid >> 7;
        const int n = n0 + px;
        const int i2 = (n >> 6) << 1, j2 = (n & 63) << 1;
        const float* src = mainf + (((size_t)(b * 64)) << 14) + i2 * 128 + j2;
#pragma unroll 4
        for (int cc = 0; cc < 32; ++cc) {
            int c = (chh << 5) | cc;
            const float2 a = *(const float2*)(src + ((size_t)c << 14));
            const float2 d = *(const float2*)(src + ((size_t)c << 14) + 128);
            xs[c][px] = 0.25f * ((a.x + a.y) + (d.x + d.y));
        }
    }
    __syncthreads();

    const int px = tid & 127, cih = tid >> 7, ci0 = cih << 4;
    float acc[16];
#pragma unroll
    for (int j = 0; j < 16; ++j) acc[j] = bs[ci0 + j];
#pragma unroll 4
    for (int c = 0; c < 64; ++c) {
        float x = xs[c][px];
#pragma unroll
        for (int j = 0; j < 16; ++j)
            acc[j] = fmaf(w[((ci0 + j) << 6) + c], x, acc[j]);
    }
    const int n = n0 + px;
    const int pix = (b << 12) + n;
    if (kind < 2) {
        if (kind == 0) {
#pragma unroll
            for (int j = 0; j < 16; ++j) acc[j] *= LOG2E;
        }
        unsigned int u[8];
#pragma unroll
        for (int i = 0; i < 8; ++i)
            u[i] = (unsigned int)f2bf_bits(acc[2 * i]) |
                   ((unsigned int)f2bf_bits(acc[2 * i + 1]) << 16);
        uint4* d4 = (uint4*)(((kind == 0) ? Qb : Kb) + (size_t)pix * 32 + ci0);
        d4[0] = make_uint4(u[0], u[1], u[2], u[3]);
        d4[1] = make_uint4(u[4], u[5], u[6], u[7]);
    } else {
#pragma unroll
        for (int j = 0; j < 16; ++j)
            Vt[((size_t)((b << 5) | (ci0 + j)) << 12) + n] = __float2bfloat16(acc[j]);
    }
}

// ---------------- Kernel 2: 32x32 MFMA flash attention + W conv ----------------
// grid (128 qtiles of 32, 4 batch) x 256 thr. Wave w owns keys [w*1024,+1024),
// 32 chunks of 32 keys. No LDS in the loop.
__global__ __launch_bounds__(256) void attn_mfma(
    const __hip_bfloat16* __restrict__ Qb, const __hip_bfloat16* __restrict__ Kb,
    const __hip_bfloat16* __restrict__ Vt, const float* __restrict__ w_w,
    const float* __restrict__ w_b, float* __restrict__ out2)
{
    __shared__ __align__(16) float redbuf[3][64][20];
    __shared__ __align__(16) float obuf[32][36];
    const int tid = threadIdx.x, lane = tid & 63, w = tid >> 6;
    const int q = lane & 31, h = lane >> 5;
    const int b = blockIdx.y, qbase = blockIdx.x << 5;
    // sigma: swap bits 2 and 3 of q (K-row permutation)
    const int sig = (q & ~12) | ((q & 4) << 1) | ((q & 8) >> 1);

    // Q B-frags: B[k=ci][n=q] -> Qb[qbase+q][ci = 8h..8h+7 (+16)]
    const __hip_bfloat16* Qrow = Qb + (((size_t)(b << 12) + qbase + q) << 5);
    const bf16x8 bq1 = *(const bf16x8*)(Qrow + 8 * h);
    const bf16x8 bq2 = *(const bf16x8*)(Qrow + 16 + 8 * h);

    const __hip_bfloat16* Kbb = Kb + ((size_t)(b << 12) << 5);
    const __hip_bfloat16* Vbb = Vt + ((size_t)(b << 5) << 12) + ((size_t)q << 12);
    const int kq = w << 10;
#define LDK1(k) (*(const bf16x8*)(Kbb + ((size_t)((k) + sig) << 5) + 8 * h))
#define LDK2(k) (*(const bf16x8*)(Kbb + ((size_t)((k) + sig) << 5) + 16 + 8 * h))
#define LDV1(k) (*(const bf16x8*)(Vbb + (k) + 8 * h))
#define LDV2(k) (*(const bf16x8*)(Vbb + (k) + 16 + 8 * h))

    f32x16 acc;
#pragma unroll
    for (int r = 0; r < 16; ++r) acc[r] = 0.f;
    const f32x16 z16 = acc;
    float den = 0.f;

    bf16x8 a1c = LDK1(kq),      a2c = LDK2(kq);
    bf16x8 v1B = LDV1(kq),      v2B = LDV2(kq);
    bf16x8 a1n = LDK1(kq + 32), a2n = LDK2(kq + 32);
    bf16x8 v1N = LDV1(kq + 32), v2N = LDV2(kq + 32);
    bf16x8 ap1, ap2, v1A, v2A;

    // ---- chunk 0: S phase only ----
    {
        f32x16 s = __builtin_amdgcn_mfma_f32_32x32x16_bf16(a1c, bq1, z16, 0, 0, 0);
        s = __builtin_amdgcn_mfma_f32_32x32x16_bf16(a2c, bq2, s, 0, 0, 0);
        float e[16];
#pragma unroll
        for (int r = 0; r < 16; ++r) e[r] = __builtin_amdgcn_exp2f(s[r]);
        den += (((e[0]+e[1])+(e[2]+e[3])) + ((e[4]+e[5])+(e[6]+e[7])))
             + (((e[8]+e[9])+(e[10]+e[11])) + ((e[12]+e[13])+(e[14]+e[15])));
        uint4 t1 = make_uint4(pk2bf(e[0],e[1]), pk2bf(e[2],e[3]),
                              pk2bf(e[4],e[5]), pk2bf(e[6],e[7]));
        uint4 t2 = make_uint4(pk2bf(e[8],e[9]), pk2bf(e[10],e[11]),
                              pk2bf(e[12],e[13]), pk2bf(e[14],e[15]));
        ap1 = *(bf16x8*)&t1; ap2 = *(bf16x8*)&t2;
    }

#pragma unroll 2
    for (int ch = 1; ch < 32; ++ch) {
        const int kn = kq + ((ch + 1) & 31) * 32;
        v1A = v1B; v2A = v2B;          // V(ch-1) for this iter's PV
        v1B = v1N; v2B = v2N;          // V(ch)
        a1c = a1n; a2c = a2n;          // K(ch)
        a1n = LDK1(kn); a2n = LDK2(kn);
        v1N = LDV1(kn); v2N = LDV2(kn);

        // S of chunk ch
        f32x16 s = __builtin_amdgcn_mfma_f32_32x32x16_bf16(a1c, bq1, z16, 0, 0, 0);
        s = __builtin_amdgcn_mfma_f32_32x32x16_bf16(a2c, bq2, s, 0, 0, 0);

        // PV of chunk ch-1 (ap packed last iteration -> independent of s)
        acc = __builtin_amdgcn_mfma_f32_32x32x16_bf16(ap1, v1A, acc, 0, 0, 0);
        acc = __builtin_amdgcn_mfma_f32_32x32x16_bf16(ap2, v2A, acc, 0, 0, 0);

        float e[16];
#pragma unroll
        for (int r = 0; r < 16; ++r) e[r] = __builtin_amdgcn_exp2f(s[r]);
        den += (((e[0]+e[1])+(e[2]+e[3])) + ((e[4]+e[5])+(e[6]+e[7])))
             + (((e[8]+e[9])+(e[10]+e[11])) + ((e[12]+e[13])+(e[14]+e[15])));
        uint4 t1 = make_uint4(pk2bf(e[0],e[1]), pk2bf(e[2],e[3]),
                              pk2bf(e[4],e[5]), pk2bf(e[6],e[7]));
        uint4 t2 = make_uint4(pk2bf(e[8],e[9]), pk2bf(e[10],e[11]),
                              pk2bf(e[12],e[13]), pk2bf(e[14],e[15]));
        ap1 = *(bf16x8*)&t1; ap2 = *(bf16x8*)&t2;
    }
    // tail: PV of chunk 31 (V(31) sits in v1B/v2B after last rotation)
    acc = __builtin_amdgcn_mfma_f32_32x32x16_bf16(ap1, v1B, acc, 0, 0, 0);
    acc = __builtin_amdgcn_mfma_f32_32x32x16_bf16(ap2, v2B, acc, 0, 0, 0);
#undef LDK1
#undef LDK2
#undef LDV1
#undef LDV2

    // den(lane) covers query q over this lane's 16 keys/chunk; other half:
    den += __shfl_xor(den, 32);

    // cross-wave combine over 4 key-quarters
    if (w) {
        float* rb = &redbuf[w - 1][lane][0];
        f32x4* rb4 = (f32x4*)rb;
#pragma unroll
        for (int p = 0; p < 4; ++p) {
            f32x4 t = {acc[4*p], acc[4*p+1], acc[4*p+2], acc[4*p+3]};
            rb4[p] = t;
        }
        rb[16] = den;
    }
    __syncthreads();
    if (w == 0) {
#pragma unroll
        for (int ww = 0; ww < 3; ++ww) {
            const float* rb = &redbuf[ww][lane][0];
            const f32x4* rb4 = (const f32x4*)rb;
#pragma unroll
            for (int p = 0; p < 4; ++p) {
                f32x4 t = rb4[p];
                acc[4*p] += t[0]; acc[4*p+1] += t[1];
                acc[4*p+2] += t[2]; acc[4*p+3] += t[3];
            }
            den += rb[16];
        }
        // O C-layout: row(query) = (r&3)+8*(r>>2)+4h, col(ci) = q
#pragma unroll
        for (int r = 0; r < 16; ++r) {
            int qr = (r & 3) + 8 * (r >> 2) + 4 * h;
            float inv = 1.0f / __shfl(den, qr);
            obuf[qr][q] = acc[r] * inv;
        }
    }
    __syncthreads();

    // ---- fused W 1x1 conv over the 32-query tile ----
    const int qq = tid & 31, cog = tid >> 5;   // 8 co per thread
    float ov[32];
    const float4* orow = (const float4*)&obuf[qq][0];
#pragma unroll
    for (int k4 = 0; k4 < 8; ++k4) {
        float4 t = orow[k4];
        ov[4*k4] = t.x; ov[4*k4+1] = t.y; ov[4*k4+2] = t.z; ov[4*k4+3] = t.w;
    }
    float* dstbase = out2 + (((size_t)(b << 6)) << 12) + qbase + qq;
#pragma unroll
    for (int kk = 0; kk < 8; ++kk) {
        int co = (kk << 3) | cog;
        const float4* wr = (const float4*)&w_w[co << 5];
        float acc2 = w_b[co];
#pragma unroll
        for (int k4 = 0; k4 < 8; ++k4) {
            float4 t = wr[k4];
            acc2 = fmaf(t.x, ov[4*k4],   acc2);
            acc2 = fmaf(t.y, ov[4*k4+1], acc2);
            acc2 = fmaf(t.z, ov[4*k4+2], acc2);
            acc2 = fmaf(t.w, ov[4*k4+3], acc2);
        }
        dstbase[(size_t)co << 12] = acc2;
    }
}

// ---------------- Kernel 3: BN partial statistics (R9 verbatim) ----------------
__global__ __launch_bounds__(256) void stats_kernel(
    const float* __restrict__ out2, float* __restrict__ stats1)
{
    int co = blockIdx.x >> 2, b = blockIdx.x & 3, t = threadIdx.x;
    const float* p = out2 + ((size_t)((b << 6) | co) << 12);
    float s = 0.f, s2 = 0.f;
#pragma unroll
    for (int ii = 0; ii < 16; ++ii) {
        float v = p[(ii << 8) | t];
        s += v; s2 = fmaf(v, v, s2);
    }
    __shared__ float rs[256], rs2[256];
    rs[t] = s; rs2[t] = s2;
    __syncthreads();
    for (int off = 128; off > 0; off >>= 1) {
        if (t < off) { rs[t] += rs[t + off]; rs2[t] += rs2[t + off]; }
        __syncthreads();
    }
    if (t == 0) {
        stats1[blockIdx.x * 2]     = rs[0];
        stats1[blockIdx.x * 2 + 1] = rs2[0];
    }
}

// ---------------- Kernel 4: BN + bilinear 64->128 + residual (R9 verbatim) ----------------
__global__ __launch_bounds__(256) void up_kernel(
    const float* __restrict__ out2, const float* __restrict__ stats1,
    const float* __restrict__ gamma, const float* __restrict__ beta,
    const float* __restrict__ mainf, float* __restrict__ out)
{
    int gid = blockIdx.x * 256 + threadIdx.x;   // < 4*64*128*32
    int j4 = (gid & 31) << 2;
    int i  = (gid >> 5) & 127;
    int co = (gid >> 12) & 63;            // uniform within a block
    int b  = gid >> 18;

    float sm = 0.f, sq = 0.f;
#pragma unroll
    for (int bb = 0; bb < 4; ++bb) {
        sm += stats1[((co << 2) | bb) * 2];
        sq += stats1[((co << 2) | bb) * 2 + 1];
    }
    float mean = sm * (1.0f / 16384.0f);
    float var  = sq * (1.0f / 16384.0f) - mean * mean;
    float inv  = rsqrtf(var + 1e-5f);
    float scale = gamma[co] * inv;
    float shift = beta[co] - mean * scale;

    int ih = i >> 1;
    int k0, k1; float wi;
    if (i & 1)       { k0 = ih;     k1 = (ih < 63) ? ih + 1 : 63; wi = 0.25f; }
    else if (ih == 0){ k0 = 0;      k1 = 0;                       wi = 0.0f;  }
    else             { k0 = ih - 1; k1 = ih;                      wi = 0.75f; }

    const float* p0r = out2 + ((size_t)((b << 6) | co) << 12) + (k0 << 6);
    const float* p1r = out2 + ((size_t)((b << 6) | co) << 12) + (k1 << 6);

    float res[4];
#pragma unroll
    for (int jj = 0; jj < 4; ++jj) {
        int j = j4 | jj;
        int il = j >> 1;
        int l0, l1; float wj;
        if (j & 1)       { l0 = il;     l1 = (il < 63) ? il + 1 : 63; wj = 0.25f; }
        else if (il == 0){ l0 = 0;      l1 = 0;                       wj = 0.0f;  }
        else             { l0 = il - 1; l1 = il;                      wj = 0.75f; }
        float v00 = p0r[l0], v01 = p0r[l1];
        float v10 = p1r[l0], v11 = p1r[l1];
        float top = v00 + wj * (v01 - v00);
        float bot = v10 + wj * (v11 - v10);
        float v = top + wi * (bot - top);
        res[jj] = fmaf(v, scale, shift);
    }
    size_t idx = (((size_t)((b << 6) | co)) << 14) + (i << 7) + j4;
    float4 m4 = *(const float4*)(mainf + idx);
    *(float4*)(out + idx) = make_float4(res[0] + m4.x, res[1] + m4.y,
                                        res[2] + m4.z, res[3] + m4.w);
}

extern "C" void kernel_launch(void* const* d_in, const int* in_sizes, int n_in,
                              void* d_out, int out_size, void* d_ws, size_t ws_size,
                              hipStream_t stream)
{
    const float* mainf = (const float*)d_in[0];
    const float* cross = (const float*)d_in[1];
    const float* g_w   = (const float*)d_in[2];
    const float* g_b   = (const float*)d_in[3];
    const float* th_w  = (const float*)d_in[4];
    const float* th_b  = (const float*)d_in[5];
    const float* ph_w  = (const float*)d_in[6];
    const float* ph_b  = (const float*)d_in[7];
    const float* w_w   = (const float*)d_in[8];
    const float* w_b   = (const float*)d_in[9];
    const float* gamma = (const float*)d_in[10];
    const float* beta  = (const float*)d_in[11];
    float* out = (float*)d_out;

    __hip_bfloat16* Qb = (__hip_bfloat16*)d_ws;     // 4*4096*32
    __hip_bfloat16* Kb = Qb + 524288;
    __hip_bfloat16* Vt = Kb + 524288;               // [b][ci][4096]
    float* out2   = (float*)(Vt + 524288);          // 4*64*4096
    float* stats1 = out2 + 1048576;                 // 512

    qkv_kernel<<<384, 256, 0, stream>>>(cross, mainf, g_w, g_b, th_w, th_b,
                                        ph_w, ph_b, Qb, Kb, Vt);
    attn_mfma<<<dim3(128, 4), 256, 0, stream>>>(Qb, Kb, Vt, w_w, w_b, out2);
    stats_kernel<<<256, 256, 0, stream>>>(out2, stats1);
    up_kernel<<<4096, 256, 0, stream>>>(out2, stats1, gamma, beta, mainf, out);
}